// Round 18
// baseline (574.165 us; speedup 1.0000x reference)
//
#include <hip/hip_runtime.h>

typedef float f32x4 __attribute__((ext_vector_type(4)));
typedef _Float16 f16x8 __attribute__((ext_vector_type(8)));

#define NBATCH 32
#define NPTS   16384
#define W_TOT  197888
#define B_TOT  1027

// ws layout (halves):
//   [0)         W hi frags, hidden layers: 32 b * 3 l * 65536
//   [6291456)   W lo frags (layers 0,1 only)
//   [12582912)  W4 hi frags: 32 b * 8 s * 512
#define WLO_OFF 6291456
#define W4_OFF  12582912
#define WS_NEEDED 25427968ull

// out layout (floats)
#define OUT_COORDS 1572864
#define OUT_W      2621440
#define OUT_B      8953856
#define OUT_LAT    8986720

// sin(30*x) via v_sin_f32 (input in revolutions): t = x*30/(2pi), fract-reduced
static __device__ __forceinline__ float fast_sin30(float x) {
    float t = x * 4.774648292756860f;
#if __has_builtin(__builtin_amdgcn_fractf)
    t = __builtin_amdgcn_fractf(t);
#else
    t -= floorf(t);
#endif
    return __builtin_amdgcn_sinf(t);
}

// sin + fp16 hi/lo split for a pair of values, packed via v_cvt_pkrtz
static __device__ __forceinline__ void sin_split_pk(float a0, float a1,
                                                    unsigned& uh, unsigned& ul) {
    float s0 = fast_sin30(a0), s1 = fast_sin30(a1);
    auto hp = __builtin_amdgcn_cvt_pkrtz(s0, s1);
    float l0 = s0 - (float)hp[0];
    float l1 = s1 - (float)hp[1];
    auto lp = __builtin_amdgcn_cvt_pkrtz(l0, l1);
    uh = __builtin_bit_cast(unsigned, hp);
    ul = __builtin_bit_cast(unsigned, lp);
}

// sin + fp16 pack, hi only (for layers whose consumer never reads act-lo)
static __device__ __forceinline__ unsigned sin_pk2(float a0, float a1) {
    float s0 = fast_sin30(a0), s1 = fast_sin30(a1);
    auto hp = __builtin_amdgcn_cvt_pkrtz(s0, s1);
    return __builtin_bit_cast(unsigned, hp);
}

// ---- pre-kernel: split W into hi/lo fp16 fragments in MFMA layout ----
// frag element order: [batch][layer][s][tile16][lane][r]
// idx16 = tile*16 + (lane&15); k = s*32 + 4*(lane>>4) + (r&3) + 16*(r>>2)
__global__ void make_wfrags(const float* __restrict__ w, _Float16* __restrict__ wf) {
    int idx = blockIdx.x * 256 + threadIdx.x;
    if (idx < 6291456) {
        int batch = idx / 196608;
        int rem   = idx - batch * 196608;
        int layer = rem >> 16;
        int rem2  = rem & 65535;
        int s     = rem2 >> 13;
        int rem3  = rem2 & 8191;
        int ntile = rem3 >> 9;
        int rem4  = rem3 & 511;
        int lane  = rem4 >> 3, r = rem4 & 7;
        int col = ntile * 16 + (lane & 15);
        int k   = s * 32 + 4 * (lane >> 4) + (r & 3) + 16 * (r >> 2);
        float v = w[(size_t)batch * W_TOT + 512 + layer * 65536 + col * 256 + k];
        _Float16 h = (_Float16)v;
        wf[idx] = h;
        if (layer < 2)   // W-lo consumed only by 3-pass layers (hidden 0, 1)
            wf[WLO_OFF + idx] = (_Float16)(v - (float)h);
    } else if (idx < 6291456 + 131072) {
        int i4 = idx - 6291456;
        int batch = i4 >> 12;
        int rem   = i4 & 4095;
        int s     = rem >> 9;
        int rem2  = rem & 511;
        int lane  = rem2 >> 3, r = rem2 & 7;
        int col = lane & 15;
        int k   = s * 32 + 4 * (lane >> 4) + (r & 3) + 16 * (r >> 2);
        float v = (col < 3) ? w[(size_t)batch * W_TOT + 197120 + col * 256 + k] : 0.0f;
        wf[W4_OFF + i4] = (_Float16)v;
    }
}

// act LDS layout, "stream" form for a 32-pt tile (conflict-free, no swizzle):
//   half index IDX(p, s, c, e) = s*1024 + c*256 + p*8 + e
//   where s = K-chunk (f>>5), c = 8-half group ((f>>2)&3), e = ((f>>4)&1)*4 + (f&3)
// B-frag read for (point p, K-chunk s, group g): ONE b128 at IDX(p,s,g,0).

// One hidden layer (256->256), 32-pt tile. NPASS: 3 / 2 / 1 as before.
template<int NPASS, bool WRITE_LO>
static __device__ __forceinline__ void hidden_layer(
    _Float16* __restrict__ Ahi, _Float16* __restrict__ Alo,
    const _Float16* __restrict__ whf, const float* __restrict__ bias_base,
    int wn, int lane, int r15, int g)
{
    const _Float16* wbase = whf + (wn * 4) * 512 + lane * 8;

    // acc[mt][nt]: mt = feat tile (wn*4+mt), nt = point tile (0,1); bias init
    f32x4 acc[4][2];
    #pragma unroll
    for (int mt = 0; mt < 4; ++mt) {
        float4 bv = *(const float4*)(bias_base + (wn * 4 + mt) * 16 + 4 * g);
        f32x4 bi = {bv.x, bv.y, bv.z, bv.w};
        #pragma unroll
        for (int nt = 0; nt < 2; ++nt) acc[mt][nt] = bi;
    }

    __builtin_amdgcn_s_setprio(1);
    #pragma unroll
    for (int s = 0; s < 8; ++s) {
        f16x8 bh[2], bl[2];
        #pragma unroll
        for (int nt = 0; nt < 2; ++nt) {
            int idx = s * 1024 + g * 256 + (nt * 16 + r15) * 8;
            bh[nt] = *(const f16x8*)&Ahi[idx];
            if (NPASS >= 2) bl[nt] = *(const f16x8*)&Alo[idx];
        }
        #pragma unroll
        for (int mt = 0; mt < 4; ++mt) {
            const _Float16* pb = wbase + s * 8192 + mt * 512;
            f16x8 wh = *(const f16x8*)pb;
            f16x8 wl;
            if (NPASS >= 3) wl = *(const f16x8*)(pb + WLO_OFF);
            #pragma unroll
            for (int nt = 0; nt < 2; ++nt) {
                acc[mt][nt] = __builtin_amdgcn_mfma_f32_16x16x32_f16(wh, bh[nt], acc[mt][nt], 0, 0, 0);
                if (NPASS >= 2)
                    acc[mt][nt] = __builtin_amdgcn_mfma_f32_16x16x32_f16(wh, bl[nt], acc[mt][nt], 0, 0, 0);
                if (NPASS >= 3)
                    acc[mt][nt] = __builtin_amdgcn_mfma_f32_16x16x32_f16(wl, bh[nt], acc[mt][nt], 0, 0, 0);
            }
        }
    }
    __builtin_amdgcn_s_setprio(0);

    // epilogue part 1 (PRE-barrier, registers only): sin (+ split) + pack.
    // chunk s' = 2*wn + a; f16x8: [0..3] = mt 2a (e=0..3), [4..7] = mt 2a+1
    uint4 chv[2][2], clv[2][2];
    #pragma unroll
    for (int nt = 0; nt < 2; ++nt) {
        #pragma unroll
        for (int a = 0; a < 2; ++a) {
            if (WRITE_LO) {
                sin_split_pk(acc[2*a  ][nt][0], acc[2*a  ][nt][1], chv[nt][a].x, clv[nt][a].x);
                sin_split_pk(acc[2*a  ][nt][2], acc[2*a  ][nt][3], chv[nt][a].y, clv[nt][a].y);
                sin_split_pk(acc[2*a+1][nt][0], acc[2*a+1][nt][1], chv[nt][a].z, clv[nt][a].z);
                sin_split_pk(acc[2*a+1][nt][2], acc[2*a+1][nt][3], chv[nt][a].w, clv[nt][a].w);
            } else {
                chv[nt][a].x = sin_pk2(acc[2*a  ][nt][0], acc[2*a  ][nt][1]);
                chv[nt][a].y = sin_pk2(acc[2*a  ][nt][2], acc[2*a  ][nt][3]);
                chv[nt][a].z = sin_pk2(acc[2*a+1][nt][0], acc[2*a+1][nt][1]);
                chv[nt][a].w = sin_pk2(acc[2*a+1][nt][2], acc[2*a+1][nt][3]);
            }
        }
    }

    // epilogue part 2: barrier, then only the vector LDS writes
    __syncthreads();   // all waves done reading old act
    #pragma unroll
    for (int nt = 0; nt < 2; ++nt) {
        int p = nt * 16 + r15;
        #pragma unroll
        for (int a = 0; a < 2; ++a) {
            int idx = (2 * wn + a) * 1024 + g * 256 + p * 8;
            *(uint4*)&Ahi[idx] = chv[nt][a];
            if (WRITE_LO) *(uint4*)&Alo[idx] = clv[nt][a];
        }
    }
    __syncthreads();   // new act visible
}

// 32-pt tile, 4 waves (wave wn owns feats [wn*64,+64) x all 32 pts).
// LDS = 32 KB -> up to 5 blocks/CU (5 waves/SIMD): post-swizzle, W is
// L2-resident so the 2x W traffic per point is cheap; independent blocks
// give the scheduler anti-phase MFMA/VALU material.
__global__ __launch_bounds__(256, 5)
void siren_mfma(const float* __restrict__ coords,
                const float* __restrict__ w,
                const float* __restrict__ b,
                const _Float16* __restrict__ wf,
                float* __restrict__ out)
{
    __shared__ _Float16 Ahi[32 * 256];
    __shared__ _Float16 Alo[32 * 256];

    // XCD-aware swizzle (T1, r17-validated): nwg = 16384 = 8 x 2048;
    // each XCD gets 2048 consecutive works = 4 whole batches -> per-XCD L2
    // holds only those batches' W frags (~3.1 MB < 4 MB).
    const int bid0 = blockIdx.x;
    const int bid  = (bid0 & 7) * 2048 + (bid0 >> 3);
    const int batch = bid >> 9, tile = bid & 511, n0 = tile * 32;
    const int t = threadIdx.x, wn = t >> 6, lane = t & 63;
    const int r15 = lane & 15, g = lane >> 4;

    const float* wb = w + (size_t)batch * W_TOT;
    const float* bb = b + (size_t)batch * B_TOT;

    // ---- layer 0 (entry): 2 -> 256 (VALU), write stream-layout act hi+lo ----
    {
        int p = t >> 3, fb = (t & 7) * 32;   // 8 threads per point, 32 feats each
        float2 c = ((const float2*)coords)[(size_t)batch * NPTS + n0 + p];
        #pragma unroll 4
        for (int j2 = 0; j2 < 32; j2 += 2) {
            int f = fb + j2;
            float4 wv = *(const float4*)(wb + 2 * f);
            float b0 = bb[f], b1 = bb[f + 1];
            float u0 = fmaf(c.x, wv.x, fmaf(c.y, wv.y, b0));
            float u1 = fmaf(c.x, wv.z, fmaf(c.y, wv.w, b1));
            unsigned uh, ul;
            sin_split_pk(u0, u1, uh, ul);
            int sf = f >> 5, cf = (f >> 2) & 3, ef = ((f >> 4) & 1) * 4 + (f & 3);
            int idx = sf * 1024 + cf * 256 + p * 8 + ef;   // ef even here
            *(unsigned*)&Ahi[idx] = uh;
            *(unsigned*)&Alo[idx] = ul;
        }
    }
    __syncthreads();

    // ---- hidden layers: 3-pass, 3-pass (hi-only out), 1-pass (r15 ladder) ----
    hidden_layer<3, true >(Ahi, Alo, wf + (size_t)(batch * 3 + 0) * 65536, bb + 256,       wn, lane, r15, g);
    hidden_layer<3, false>(Ahi, Alo, wf + (size_t)(batch * 3 + 1) * 65536, bb + 256 + 256, wn, lane, r15, g);
    hidden_layer<1, false>(Ahi, Alo, wf + (size_t)(batch * 3 + 2) * 65536, bb + 256 + 512, wn, lane, r15, g);

    // ---- layer 4: 256 -> 3 (hi only); waves 0,1 take point tiles 0,1 ----
    if (wn < 2) {
        f32x4 acc4 = {};
        const _Float16* w4 = wf + W4_OFF + batch * 4096;
        #pragma unroll
        for (int s = 0; s < 8; ++s) {
            int p = wn * 16 + r15;
            int idx = s * 1024 + g * 256 + p * 8;
            f16x8 bh = *(const f16x8*)&Ahi[idx];
            f16x8 w4f = *(const f16x8*)(w4 + s * 512 + lane * 8);
            acc4 = __builtin_amdgcn_mfma_f32_16x16x32_f16(w4f, bh, acc4, 0, 0, 0);
        }
        if (g == 0) {   // rows 0..2 = the 3 outputs; col = point
            int p = wn * 16 + r15;
            float* po = out + ((size_t)batch * NPTS + n0 + p) * 3;
            #pragma unroll
            for (int j = 0; j < 3; ++j)
                po[j] = acc4[j] + bb[1024 + j];
        }
    }
}

// ---- fallback fp32 kernel (used only if ws too small) ----
__global__ __launch_bounds__(256, 2)
void siren_fwd_fp32(const float* __restrict__ coords,
                    const float* __restrict__ w,
                    const float* __restrict__ b,
                    float* __restrict__ out)
{
    __shared__ float A[256][64 + 4];
    const int bid = blockIdx.x, batch = bid >> 8, tile = bid & 255;
    const int t = threadIdx.x, n0 = tile * 64;
    const float* wb = w + (size_t)batch * W_TOT;
    const float* bb = b + (size_t)batch * B_TOT;
    const float2* c2 = (const float2*)(coords + (size_t)(batch * NPTS + n0) * 2);
    {
        const float w0 = wb[t * 2 + 0], w1 = wb[t * 2 + 1], b0 = bb[t];
        for (int p = 0; p < 64; ++p) {
            const float2 c = c2[p];
            A[t][p] = fast_sin30(fmaf(c.x, w0, fmaf(c.y, w1, b0)));
        }
    }
    __syncthreads();
    for (int li = 0; li < 3; ++li) {
        const float* Wl = wb + 512 + li * 65536 + t * 256;
        const float bo = bb[256 + li * 256 + t];
        float res[64];
        for (int pb = 0; pb < 2; ++pb) {
            float acc[32];
            #pragma unroll
            for (int i = 0; i < 32; ++i) acc[i] = bo;
            for (int k = 0; k < 256; k += 4) {
                const float4 wv = *(const float4*)(Wl + k);
                #pragma unroll
                for (int kk = 0; kk < 4; ++kk) {
                    const float wk = (&wv.x)[kk];
                    const float* ar = &A[k + kk][pb * 32];
                    #pragma unroll
                    for (int i = 0; i < 32; i += 4) {
                        const float4 a4 = *(const float4*)(ar + i);
                        acc[i + 0] = fmaf(a4.x, wk, acc[i + 0]);
                        acc[i + 1] = fmaf(a4.y, wk, acc[i + 1]);
                        acc[i + 2] = fmaf(a4.z, wk, acc[i + 2]);
                        acc[i + 3] = fmaf(a4.w, wk, acc[i + 3]);
                    }
                }
            }
            #pragma unroll
            for (int i = 0; i < 32; ++i) res[pb * 32 + i] = fast_sin30(acc[i]);
        }
        __syncthreads();
        for (int p = 0; p < 64; p += 4)
            *(float4*)&A[t][p] = make_float4(res[p], res[p+1], res[p+2], res[p+3]);
        __syncthreads();
    }
    if (t < 192) {
        const int o = t >> 6, p = t & 63;
        const float* W4 = wb + 197120 + o * 256;
        float acc = bb[1024 + o];
        for (int k = 0; k < 256; k += 4) {
            const float4 wv = *(const float4*)(W4 + k);
            acc = fmaf(A[k+0][p], wv.x, acc);
            acc = fmaf(A[k+1][p], wv.y, acc);
            acc = fmaf(A[k+2][p], wv.z, acc);
            acc = fmaf(A[k+3][p], wv.w, acc);
        }
        out[(size_t)(batch * NPTS + n0 + p) * 3 + o] = acc;
    }
}

extern "C" void kernel_launch(void* const* d_in, const int* in_sizes, int n_in,
                              void* d_out, int out_size, void* d_ws, size_t ws_size,
                              hipStream_t stream)
{
    const float* coords = (const float*)d_in[0];
    const float* w      = (const float*)d_in[1];
    const float* bvec   = (const float*)d_in[2];
    const float* latent = (const float*)d_in[3];
    float* out = (float*)d_out;

    if (ws_size >= WS_NEEDED) {
        _Float16* wf = (_Float16*)d_ws;
        make_wfrags<<<25088, 256, 0, stream>>>(w, wf);
        siren_mfma<<<NBATCH * (NPTS / 32), 256, 0, stream>>>(coords, w, bvec, wf, out);
    } else {
        siren_fwd_fp32<<<NBATCH * (NPTS / 64), 256, 0, stream>>>(coords, w, bvec, out);
    }

    hipMemcpyAsync(out + OUT_COORDS, coords, (size_t)1048576 * sizeof(float),
                   hipMemcpyDeviceToDevice, stream);
    hipMemcpyAsync(out + OUT_W,      w,      (size_t)6332416 * sizeof(float),
                   hipMemcpyDeviceToDevice, stream);
    hipMemcpyAsync(out + OUT_B,      bvec,   (size_t)32864   * sizeof(float),
                   hipMemcpyDeviceToDevice, stream);
    hipMemcpyAsync(out + OUT_LAT,    latent, (size_t)8192    * sizeof(float),
                   hipMemcpyDeviceToDevice, stream);
}

// Round 19
// 453.920 us; speedup vs baseline: 1.2649x; 1.2649x over previous
//
#include <hip/hip_runtime.h>

typedef float f32x4 __attribute__((ext_vector_type(4)));
typedef _Float16 f16x8 __attribute__((ext_vector_type(8)));

#define NBATCH 32
#define NPTS   16384
#define W_TOT  197888
#define B_TOT  1027

// ws layout (halves):
//   [0)         W hi frags, hidden layers: 32 b * 3 l * 65536
//   [6291456)   W lo frags (layers 0,1 only)
//   [12582912)  W4 hi frags: 32 b * 8 s * 512
#define WLO_OFF 6291456
#define W4_OFF  12582912
#define WS_NEEDED 25427968ull

// out layout (floats)
#define OUT_COORDS 1572864
#define OUT_W      2621440
#define OUT_B      8953856
#define OUT_LAT    8986720

// sin(30*x) via v_sin_f32 (input in revolutions): t = x*30/(2pi), fract-reduced
static __device__ __forceinline__ float fast_sin30(float x) {
    float t = x * 4.774648292756860f;
#if __has_builtin(__builtin_amdgcn_fractf)
    t = __builtin_amdgcn_fractf(t);
#else
    t -= floorf(t);
#endif
    return __builtin_amdgcn_sinf(t);
}

// sin + fp16 hi/lo split for a pair of values, packed via v_cvt_pkrtz
static __device__ __forceinline__ void sin_split_pk(float a0, float a1,
                                                    unsigned& uh, unsigned& ul) {
    float s0 = fast_sin30(a0), s1 = fast_sin30(a1);
    auto hp = __builtin_amdgcn_cvt_pkrtz(s0, s1);
    float l0 = s0 - (float)hp[0];
    float l1 = s1 - (float)hp[1];
    auto lp = __builtin_amdgcn_cvt_pkrtz(l0, l1);
    uh = __builtin_bit_cast(unsigned, hp);
    ul = __builtin_bit_cast(unsigned, lp);
}

// sin + fp16 pack, hi only (for layers whose consumer never reads act-lo)
static __device__ __forceinline__ unsigned sin_pk2(float a0, float a1) {
    float s0 = fast_sin30(a0), s1 = fast_sin30(a1);
    auto hp = __builtin_amdgcn_cvt_pkrtz(s0, s1);
    return __builtin_bit_cast(unsigned, hp);
}

// ---- pre-kernel: split W into hi/lo fp16 fragments in MFMA layout ----
// frag element order: [batch][layer][s][tile16][lane][r]
// idx16 = tile*16 + (lane&15); k = s*32 + 4*(lane>>4) + (r&3) + 16*(r>>2)
__global__ void make_wfrags(const float* __restrict__ w, _Float16* __restrict__ wf) {
    int idx = blockIdx.x * 256 + threadIdx.x;
    if (idx < 6291456) {
        int batch = idx / 196608;
        int rem   = idx - batch * 196608;
        int layer = rem >> 16;
        int rem2  = rem & 65535;
        int s     = rem2 >> 13;
        int rem3  = rem2 & 8191;
        int ntile = rem3 >> 9;
        int rem4  = rem3 & 511;
        int lane  = rem4 >> 3, r = rem4 & 7;
        int col = ntile * 16 + (lane & 15);
        int k   = s * 32 + 4 * (lane >> 4) + (r & 3) + 16 * (r >> 2);
        float v = w[(size_t)batch * W_TOT + 512 + layer * 65536 + col * 256 + k];
        _Float16 h = (_Float16)v;
        wf[idx] = h;
        if (layer < 2)   // W-lo consumed only by 3-pass layers (hidden 0, 1)
            wf[WLO_OFF + idx] = (_Float16)(v - (float)h);
    } else if (idx < 6291456 + 131072) {
        int i4 = idx - 6291456;
        int batch = i4 >> 12;
        int rem   = i4 & 4095;
        int s     = rem >> 9;
        int rem2  = rem & 511;
        int lane  = rem2 >> 3, r = rem2 & 7;
        int col = lane & 15;
        int k   = s * 32 + 4 * (lane >> 4) + (r & 3) + 16 * (r >> 2);
        float v = (col < 3) ? w[(size_t)batch * W_TOT + 197120 + col * 256 + k] : 0.0f;
        wf[W4_OFF + i4] = (_Float16)v;
    }
}

// act LDS layout, "stream" form (conflict-free, no swizzle):
//   half index IDX(p, s, c, e) = s*2048 + c*512 + p*8 + e
//   where s = K-chunk (f>>5), c = 8-half group ((f>>2)&3), e = ((f>>4)&1)*4 + (f&3)
// B-frag read for (point p, K-chunk s, group g): ONE b128 at IDX(p,s,g,0).

// One hidden layer (256->256). NPASS: 3 = hh+hl+lh, 2 = hh+hl, 1 = hh only.
// WRITE_LO: epilogue stores act-lo (needed iff next layer reads bl).
// NPASS_NEXT: next consumer (3 = prefetch hi+lo, 1 = hi only, 0 = L4 single frag).
// pwh/pwl carry the prefetched s=0 W frags across the barrier pair.
template<int NPASS, bool WRITE_LO, int NPASS_NEXT>
static __device__ __forceinline__ void hidden_layer(
    _Float16* __restrict__ Ahi, _Float16* __restrict__ Alo,
    const _Float16* __restrict__ whf, const float* __restrict__ bias_base,
    const _Float16* __restrict__ whf_next,
    f16x8 (&pwh)[4], f16x8 (&pwl)[4],
    int wn, int lane, int r15, int g)
{
    const _Float16* wbase = whf + (wn * 4) * 512 + lane * 8;

    // acc[mt][nt]: mt = feat tile (wn*4+mt), nt = point tile; bias init
    f32x4 acc[4][4];
    #pragma unroll
    for (int mt = 0; mt < 4; ++mt) {
        float4 bv = *(const float4*)(bias_base + (wn * 4 + mt) * 16 + 4 * g);
        f32x4 bi = {bv.x, bv.y, bv.z, bv.w};
        #pragma unroll
        for (int nt = 0; nt < 4; ++nt) acc[mt][nt] = bi;
    }

    __builtin_amdgcn_s_setprio(1);
    #pragma unroll
    for (int s = 0; s < 8; ++s) {
        f16x8 bh[4], bl[4];
        #pragma unroll
        for (int nt = 0; nt < 4; ++nt) {
            int idx = s * 2048 + g * 512 + (nt * 16 + r15) * 8;
            bh[nt] = *(const f16x8*)&Ahi[idx];
            if (NPASS >= 2) bl[nt] = *(const f16x8*)&Alo[idx];
        }
        #pragma unroll
        for (int mt = 0; mt < 4; ++mt) {
            f16x8 wh, wl;
            if (s == 0) {          // prefetched across the previous barrier
                wh = pwh[mt];
                if (NPASS >= 3) wl = pwl[mt];
            } else {
                const _Float16* pb = wbase + s * 8192 + mt * 512;
                wh = *(const f16x8*)pb;
                if (NPASS >= 3) wl = *(const f16x8*)(pb + WLO_OFF);
            }
            #pragma unroll
            for (int nt = 0; nt < 4; ++nt) {
                acc[mt][nt] = __builtin_amdgcn_mfma_f32_16x16x32_f16(wh, bh[nt], acc[mt][nt], 0, 0, 0);
                if (NPASS >= 2)
                    acc[mt][nt] = __builtin_amdgcn_mfma_f32_16x16x32_f16(wh, bl[nt], acc[mt][nt], 0, 0, 0);
                if (NPASS >= 3)
                    acc[mt][nt] = __builtin_amdgcn_mfma_f32_16x16x32_f16(wl, bh[nt], acc[mt][nt], 0, 0, 0);
            }
        }
    }
    __builtin_amdgcn_s_setprio(0);

    // prefetch next layer's s=0 W frags NOW: the epilogue pack + LDS writes
    // (~1+ kcyc) hide the L2 latency; the syncthreads vmcnt-drain guarantees
    // arrival; next layer's s=0 consumes registers.
    if (NPASS_NEXT == 0) {
        pwh[0] = *(const f16x8*)(whf_next + lane * 8);
    } else {
        #pragma unroll
        for (int mt = 0; mt < 4; ++mt) {
            const _Float16* pb = whf_next + (wn * 4 + mt) * 512 + lane * 8;
            pwh[mt] = *(const f16x8*)pb;
            if (NPASS_NEXT >= 3) pwl[mt] = *(const f16x8*)(pb + WLO_OFF);
        }
    }

    // epilogue part 1 (PRE-barrier, registers only): sin (+ split) + pack.
    // chunk s' = 2*wn + a; f16x8: [0..3] = mt 2a (e=0..3), [4..7] = mt 2a+1
    uint4 chv[4][2], clv[4][2];
    #pragma unroll
    for (int nt = 0; nt < 4; ++nt) {
        #pragma unroll
        for (int a = 0; a < 2; ++a) {
            if (WRITE_LO) {
                sin_split_pk(acc[2*a  ][nt][0], acc[2*a  ][nt][1], chv[nt][a].x, clv[nt][a].x);
                sin_split_pk(acc[2*a  ][nt][2], acc[2*a  ][nt][3], chv[nt][a].y, clv[nt][a].y);
                sin_split_pk(acc[2*a+1][nt][0], acc[2*a+1][nt][1], chv[nt][a].z, clv[nt][a].z);
                sin_split_pk(acc[2*a+1][nt][2], acc[2*a+1][nt][3], chv[nt][a].w, clv[nt][a].w);
            } else {
                chv[nt][a].x = sin_pk2(acc[2*a  ][nt][0], acc[2*a  ][nt][1]);
                chv[nt][a].y = sin_pk2(acc[2*a  ][nt][2], acc[2*a  ][nt][3]);
                chv[nt][a].z = sin_pk2(acc[2*a+1][nt][0], acc[2*a+1][nt][1]);
                chv[nt][a].w = sin_pk2(acc[2*a+1][nt][2], acc[2*a+1][nt][3]);
            }
        }
    }

    // epilogue part 2: barrier, then only the vector LDS writes
    __syncthreads();   // all waves done reading old act
    #pragma unroll
    for (int nt = 0; nt < 4; ++nt) {
        int p = nt * 16 + r15;
        #pragma unroll
        for (int a = 0; a < 2; ++a) {
            int idx = (2 * wn + a) * 2048 + g * 512 + p * 8;
            *(uint4*)&Ahi[idx] = chv[nt][a];
            if (WRITE_LO) *(uint4*)&Alo[idx] = clv[nt][a];
        }
    }
    __syncthreads();   // new act visible
}

// D = W(A-op, feats) x act(B-op, points); D col = point, row = feat.
__global__ __launch_bounds__(256, 2)
void siren_mfma(const float* __restrict__ coords,
                const float* __restrict__ w,
                const float* __restrict__ b,
                const _Float16* __restrict__ wf,
                float* __restrict__ out)
{
    __shared__ _Float16 Ahi[64 * 256];
    __shared__ _Float16 Alo[64 * 256];

    // XCD-aware swizzle (T1, r17-validated): each XCD owns 1024 consecutive
    // works = 4 whole batches -> per-XCD L2 holds just those W frags (~3.1 MB).
    const int bid0 = blockIdx.x;
    const int bid  = (bid0 & 7) * 1024 + (bid0 >> 3);
    const int batch = bid >> 8, tile = bid & 255, n0 = tile * 64;
    const int t = threadIdx.x, wn = t >> 6, lane = t & 63;
    const int r15 = lane & 15, g = lane >> 4;

    const float* wb = w + (size_t)batch * W_TOT;
    const float* bb = b + (size_t)batch * B_TOT;
    const _Float16* whf0 = wf + (size_t)(batch * 3 + 0) * 65536;
    const _Float16* whf1 = wf + (size_t)(batch * 3 + 1) * 65536;
    const _Float16* whf2 = wf + (size_t)(batch * 3 + 2) * 65536;
    const _Float16* w4   = wf + W4_OFF + batch * 4096;

    // ---- layer 0 (entry): 2 -> 256 (VALU), conflict-free stream writes ----
    // lane l: point p = wn*16 + (l>>2), elem pair e = 2*(l&3) -> wave writes
    // 256B-contiguous u32 runs per (s,c) iteration (0 bank conflicts).
    {
        int p  = (wn << 4) + (lane >> 2);
        int hf = (lane & 3) >> 1, jf = (lane & 1) * 2;
        float2 c = ((const float2*)coords)[(size_t)batch * NPTS + n0 + p];
        #pragma unroll
        for (int s = 0; s < 8; ++s) {
            #pragma unroll
            for (int cf = 0; cf < 4; ++cf) {
                int f0 = s * 32 + hf * 16 + cf * 4 + jf;
                float4 wv = *(const float4*)(wb + 2 * f0);
                float2 b2 = *(const float2*)(bb + f0);
                float u0 = fmaf(c.x, wv.x, fmaf(c.y, wv.y, b2.x));
                float u1 = fmaf(c.x, wv.z, fmaf(c.y, wv.w, b2.y));
                unsigned uh, ul;
                sin_split_pk(u0, u1, uh, ul);
                int idx = s * 2048 + cf * 512 + p * 8 + hf * 4 + jf;
                *(unsigned*)&Ahi[idx] = uh;
                *(unsigned*)&Alo[idx] = ul;
            }
        }
    }

    // prefetch hidden-0's s=0 W frags before the barrier (drain hides latency)
    f16x8 pwh[4], pwl[4];
    #pragma unroll
    for (int mt = 0; mt < 4; ++mt) {
        const _Float16* pb = whf0 + (wn * 4 + mt) * 512 + lane * 8;
        pwh[mt] = *(const f16x8*)pb;
        pwl[mt] = *(const f16x8*)(pb + WLO_OFF);
    }
    __syncthreads();

    // ---- hidden layers: 3-pass, 3-pass (hi-only out), 1-pass (r15 ladder) ----
    hidden_layer<3, true , 3>(Ahi, Alo, whf0, bb + 256,       whf1, pwh, pwl, wn, lane, r15, g);
    hidden_layer<3, false, 1>(Ahi, Alo, whf1, bb + 256 + 256, whf2, pwh, pwl, wn, lane, r15, g);
    hidden_layer<1, false, 0>(Ahi, Alo, whf2, bb + 256 + 512, w4,   pwh, pwl, wn, lane, r15, g);

    // ---- layer 4: 256 -> 3 (hi only); s=0 W comes from the prefetch ----
    {
        f32x4 acc4 = {};
        #pragma unroll
        for (int s = 0; s < 8; ++s) {
            int p = wn * 16 + r15;
            int idx = s * 2048 + g * 512 + p * 8;
            f16x8 bh = *(const f16x8*)&Ahi[idx];
            f16x8 w4f = (s == 0) ? pwh[0]
                                 : *(const f16x8*)(w4 + s * 512 + lane * 8);
            acc4 = __builtin_amdgcn_mfma_f32_16x16x32_f16(w4f, bh, acc4, 0, 0, 0);
        }
        if (g == 0) {   // rows 0..2 = the 3 outputs; col = point
            int p = wn * 16 + r15;
            float* po = out + ((size_t)batch * NPTS + n0 + p) * 3;
            #pragma unroll
            for (int j = 0; j < 3; ++j)
                po[j] = acc4[j] + bb[1024 + j];
        }
    }
}

// ---- fallback fp32 kernel (used only if ws too small) ----
__global__ __launch_bounds__(256, 2)
void siren_fwd_fp32(const float* __restrict__ coords,
                    const float* __restrict__ w,
                    const float* __restrict__ b,
                    float* __restrict__ out)
{
    __shared__ float A[256][64 + 4];
    const int bid = blockIdx.x, batch = bid >> 8, tile = bid & 255;
    const int t = threadIdx.x, n0 = tile * 64;
    const float* wb = w + (size_t)batch * W_TOT;
    const float* bb = b + (size_t)batch * B_TOT;
    const float2* c2 = (const float2*)(coords + (size_t)(batch * NPTS + n0) * 2);
    {
        const float w0 = wb[t * 2 + 0], w1 = wb[t * 2 + 1], b0 = bb[t];
        for (int p = 0; p < 64; ++p) {
            const float2 c = c2[p];
            A[t][p] = fast_sin30(fmaf(c.x, w0, fmaf(c.y, w1, b0)));
        }
    }
    __syncthreads();
    for (int li = 0; li < 3; ++li) {
        const float* Wl = wb + 512 + li * 65536 + t * 256;
        const float bo = bb[256 + li * 256 + t];
        float res[64];
        for (int pb = 0; pb < 2; ++pb) {
            float acc[32];
            #pragma unroll
            for (int i = 0; i < 32; ++i) acc[i] = bo;
            for (int k = 0; k < 256; k += 4) {
                const float4 wv = *(const float4*)(Wl + k);
                #pragma unroll
                for (int kk = 0; kk < 4; ++kk) {
                    const float wk = (&wv.x)[kk];
                    const float* ar = &A[k + kk][pb * 32];
                    #pragma unroll
                    for (int i = 0; i < 32; i += 4) {
                        const float4 a4 = *(const float4*)(ar + i);
                        acc[i + 0] = fmaf(a4.x, wk, acc[i + 0]);
                        acc[i + 1] = fmaf(a4.y, wk, acc[i + 1]);
                        acc[i + 2] = fmaf(a4.z, wk, acc[i + 2]);
                        acc[i + 3] = fmaf(a4.w, wk, acc[i + 3]);
                    }
                }
            }
            #pragma unroll
            for (int i = 0; i < 32; ++i) res[pb * 32 + i] = fast_sin30(acc[i]);
        }
        __syncthreads();
        for (int p = 0; p < 64; p += 4)
            *(float4*)&A[t][p] = make_float4(res[p], res[p+1], res[p+2], res[p+3]);
        __syncthreads();
    }
    if (t < 192) {
        const int o = t >> 6, p = t & 63;
        const float* W4 = wb + 197120 + o * 256;
        float acc = bb[1024 + o];
        for (int k = 0; k < 256; k += 4) {
            const float4 wv = *(const float4*)(W4 + k);
            acc = fmaf(A[k+0][p], wv.x, acc);
            acc = fmaf(A[k+1][p], wv.y, acc);
            acc = fmaf(A[k+2][p], wv.z, acc);
            acc = fmaf(A[k+3][p], wv.w, acc);
        }
        out[(size_t)(batch * NPTS + n0 + p) * 3 + o] = acc;
    }
}

extern "C" void kernel_launch(void* const* d_in, const int* in_sizes, int n_in,
                              void* d_out, int out_size, void* d_ws, size_t ws_size,
                              hipStream_t stream)
{
    const float* coords = (const float*)d_in[0];
    const float* w      = (const float*)d_in[1];
    const float* bvec   = (const float*)d_in[2];
    const float* latent = (const float*)d_in[3];
    float* out = (float*)d_out;

    if (ws_size >= WS_NEEDED) {
        _Float16* wf = (_Float16*)d_ws;
        make_wfrags<<<25088, 256, 0, stream>>>(w, wf);
        siren_mfma<<<NBATCH * (NPTS / 64), 256, 0, stream>>>(coords, w, bvec, wf, out);
    } else {
        siren_fwd_fp32<<<NBATCH * (NPTS / 64), 256, 0, stream>>>(coords, w, bvec, out);
    }

    hipMemcpyAsync(out + OUT_COORDS, coords, (size_t)1048576 * sizeof(float),
                   hipMemcpyDeviceToDevice, stream);
    hipMemcpyAsync(out + OUT_W,      w,      (size_t)6332416 * sizeof(float),
                   hipMemcpyDeviceToDevice, stream);
    hipMemcpyAsync(out + OUT_B,      bvec,   (size_t)32864   * sizeof(float),
                   hipMemcpyDeviceToDevice, stream);
    hipMemcpyAsync(out + OUT_LAT,    latent, (size_t)8192    * sizeof(float),
                   hipMemcpyDeviceToDevice, stream);
}